// Round 16
// baseline (72.198 us; speedup 1.0000x reference)
//
#include <hip/hip_runtime.h>
#include <hip/hip_bf16.h>
#include <math.h>

// MoBoAligner forward — closed-form O(B*I*J) reformulation.
//
//   val[b,i,j]   = soft_ok ? (dot/256 - log(-log(u)))/temp : -1000
//   S_geq[b,i,k] = LSE_{j>=k} val[b,i,j]                (reverse cum-LSE)
//   g_i[p] = alpha_i[p] - S_geq[i][p+1]  (-inf if p==J-1 or !mel_mask[p])
//   C_i    = prefix cumLSE of g_i
//   alpha_{i+1}[j] = val[i][j-1] + C_i[j-2]    (masked j >= i+1)
//   w[i][q]  = exp(S_geq[i][q] + C_i[q-1]) + (J-q)*e^-10   ( = exp(delta) )
//   delta = log(w)  and  expanded = sum_i w * text   (kernelCD)
//
// r10-r15 ledger: every load/store schedule (1/3/8-deep, group-batch,
// store-batch) lands at ~43-80 us -> kernelB is ISSUE-BOUND at a low
// effective clock (~0.8 GHz; 4/256 CUs never ramp DVFS). Only lever:
// instruction slots, transcendentals weighted ~4x. This round: kernelB
// stores the (S+Ts, sel) PAIR instead of materializing w (removes 8 exp2
// + 8 fma + floor math per iter); kernelCD reconstructs w with the exact
// same f32 expression (bit-identical). Body otherwise = r13 (passed).
//
// Scale analysis (exact): true alpha <= 0, S_geq non-increasing and bimodal
// {normal >= -216, collapsed <= -1434 log2 units for temp in [0.1,1]}.
// Spike classification on S[p+1] < CUTF is off-chain; tail scale
// Tfix = 1442.7/temp + 40 bounds all spikes; collapsed-S positions form a
// suffix, so head/tail prefix sums at two fixed scales are exact to ulp.
// MIDCLAMP guards dead-zone garbage; Asel=0 marks dead alpha.

#define B_ 4
#define I_ 64
#define J_ 512
#define D_ 256

#define NEGINF (-INFINITY)
#define LOG2E 1.4426950408889634f
#define CUTF (-720.0f)     // S bimodal split (log2 units), all temp in [0.1,1]
#define MIDCLAMP 60.0f     // overflow guard for dead-zone / garbage args
#define FLOORK 4.5399929762484854e-05f  // e^-10

// ---------------- Threefry-2x32-20, key = (0, 42) --------------------------
__device__ __forceinline__ void tf2x32(unsigned int x0, unsigned int x1,
                                       unsigned int& y0, unsigned int& y1) {
  const unsigned int k0 = 0u, k1 = 42u;
  const unsigned int k2 = k0 ^ k1 ^ 0x1BD11BDAu;
  x0 += k0; x1 += k1;
#define TFR(r) { x0 += x1; x1 = (x1 << r) | (x1 >> (32 - r)); x1 ^= x0; }
  TFR(13) TFR(15) TFR(26) TFR(6)   x0 += k1; x1 += k2 + 1u;
  TFR(17) TFR(29) TFR(16) TFR(24)  x0 += k2; x1 += k0 + 2u;
  TFR(13) TFR(15) TFR(26) TFR(6)   x0 += k0; x1 += k1 + 3u;
  TFR(17) TFR(29) TFR(16) TFR(24)  x0 += k1; x1 += k2 + 4u;
  TFR(13) TFR(15) TFR(26) TFR(6)   x0 += k2; x1 += k0 + 5u;
#undef TFR
  y0 = x0; y1 = x1;
}

__device__ __forceinline__ unsigned int rand_bits(unsigned int n) {
  unsigned int y0, y1;
  tf2x32(0u, n, y0, y1);
  return y0 ^ y1;
}

// log(-log(u)) with u = jax.random.uniform(key(42), ..., 1e-20, 1.0)[n]
__device__ __forceinline__ float gumbel_term(unsigned int n) {
  unsigned int bits = rand_bits(n);
  float f = __uint_as_float((bits >> 9) | 0x3f800000u) - 1.0f;  // [0,1)
  float u = fmaxf(f + 1e-20f, 1e-20f);
  return logf(-logf(u));
}

// ---------------- streaming logsumexp pairs (kernelA, natural log) ---------
struct MS { float m; float s; };

__device__ __forceinline__ MS ms_comb(MS a, MS b) {
  if (b.m == NEGINF) return a;
  if (a.m == NEGINF) return b;
  MS r;
  if (a.m >= b.m) { r.m = a.m; r.s = a.s + b.s * __expf(b.m - a.m); }
  else            { r.m = b.m; r.s = b.s + a.s * __expf(a.m - b.m); }
  return r;
}
__device__ __forceinline__ MS ms_add(MS a, float x) {
  if (x == NEGINF) return a;
  if (a.m == NEGINF) { MS r; r.m = x; r.s = 1.0f; return r; }
  MS r;
  if (a.m >= x) { r.m = a.m; r.s = a.s + __expf(x - a.m); }
  else          { r.m = x;   r.s = 1.0f + a.s * __expf(a.m - x); }
  return r;
}
__device__ __forceinline__ float ms_val(MS a) {
  if (a.m == NEGINF) return NEGINF;
  return a.m + __logf(a.s);
}

__device__ __forceinline__ MS wave_incl_scan(MS v, int lane) {
  #pragma unroll
  for (int off = 1; off < 64; off <<= 1) {
    float mo = __shfl_up(v.m, off, 64);
    float so = __shfl_up(v.s, off, 64);
    if (lane >= off) { MS o; o.m = mo; o.s = so; v = ms_comb(o, v); }
  }
  return v;
}

// ---------------- DPP helpers (kernelB) ------------------------------------
template<int CTRL, int RM, int BM, bool BC>
__device__ __forceinline__ float dppf(float oldv, float src) {
  return __int_as_float(__builtin_amdgcn_update_dpp(
      __float_as_int(oldv), __float_as_int(src), CTRL, RM, BM, BC));
}

// inclusive float add-scan over 64 lanes (invalid sources contribute 0)
__device__ __forceinline__ float wave_incl_add_f(float x) {
  x += dppf<0x111, 0xf, 0xf, false>(0.0f, x);  // row_shr:1
  x += dppf<0x112, 0xf, 0xf, false>(0.0f, x);  // row_shr:2
  x += dppf<0x114, 0xf, 0xf, false>(0.0f, x);  // row_shr:4
  x += dppf<0x118, 0xf, 0xf, false>(0.0f, x);  // row_shr:8
  x += dppf<0x142, 0xa, 0xf, false>(0.0f, x);  // row_bcast:15 -> rows 1,3
  x += dppf<0x143, 0xc, 0xf, false>(0.0f, x);  // row_bcast:31 -> rows 2,3
  return x;
}

// ---------------- mask helpers (bool-bytes vs int32 auto-detect) -----------
__device__ __forceinline__ bool mask_is_byte(const unsigned char* p) {
  const unsigned int* w = (const unsigned int*)p;
  unsigned int orbits = 0;
  #pragma unroll
  for (int k = 0; k < 16; k++) orbits |= w[k];
  return (orbits & 0xFFFFFF00u) != 0u;  // any high byte set -> byte layout
}
__device__ __forceinline__ int mask_get(const unsigned char* p, int idx, bool isbyte) {
  return isbyte ? (p[idx] != 0) : (((const int*)p)[idx] != 0);
}

// ============ Kernel A: val + S_geq per (b,i) row (stored in log2 domain) ==
__global__ __launch_bounds__(512) void kernelA(
    const float* __restrict__ text, const float* __restrict__ mel,
    const unsigned char* __restrict__ tmask, const unsigned char* __restrict__ mmask,
    const float* __restrict__ tratio,
    float* __restrict__ val2, float* __restrict__ sgeq2) {
  int bi = blockIdx.x;
  int b = bi >> 6, i = bi & 63;
  int tid = threadIdx.x;

  __shared__ float t_s[D_];
  __shared__ float v_s[J_];
  __shared__ int sh_ilen, sh_tok, sh_mbyte;

  if (tid == 0) {
    bool tbyte = mask_is_byte(tmask);
    int ilen = 0;
    for (int k = 0; k < I_; k++) ilen += mask_get(tmask, b * I_ + k, tbyte);
    sh_ilen = ilen;
    sh_tok = mask_get(tmask, b * I_ + i, tbyte);
    sh_mbyte = mask_is_byte(mmask) ? 1 : 0;
  }
  if (tid < D_) t_s[tid] = text[(size_t)(b * I_ + i) * D_ + tid];
  __syncthreads();

  int j = tid;  // 512 threads = one j each
  const float4* m4 = (const float4*)(mel + (size_t)(b * J_ + j) * D_);
  const float4* t4 = (const float4*)t_s;
  float4 acc; acc.x = acc.y = acc.z = acc.w = 0.0f;
  #pragma unroll 8
  for (int d4 = 0; d4 < D_ / 4; ++d4) {
    float4 a = m4[d4]; float4 t = t4[d4];
    acc.x += a.x * t.x; acc.y += a.y * t.y;
    acc.z += a.z * t.z; acc.w += a.w * t.w;
  }
  float dot = (acc.x + acc.y) + (acc.z + acc.w);

  float temp = 0.1f + 0.9f * tratio[0];
  float gum = gumbel_term((unsigned)((b * I_ + i) * J_ + j));
  float e = (dot * (1.0f / 256.0f) - gum) / temp;
  int mok = mask_get(mmask, b * J_ + j, sh_mbyte != 0);
  int hi = J_ - sh_ilen + i + 1;
  bool ok = (j >= i + 1) && (j <= hi) && mok && sh_tok;
  float v = ok ? e : -1000.0f;
  v_s[j] = v;                                   // natural log domain (internal)
  val2[(size_t)bi * J_ + j] = v * LOG2E;        // log2 domain for kernelB
  __syncthreads();

  // reverse cumulative LSE by wave 0: p = reversed index, lane l owns p=l*8+e
  if (tid < 64) {
    int l = tid;
    float xs[8];
    MS tot; tot.m = NEGINF; tot.s = 0.0f;
    #pragma unroll
    for (int e = 0; e < 8; e++) {
      int p = l * 8 + e;
      xs[e] = v_s[J_ - 1 - p];
      tot = ms_add(tot, xs[e]);
    }
    MS inc = wave_incl_scan(tot, l);
    MS ex; ex.m = __shfl_up(inc.m, 1, 64); ex.s = __shfl_up(inc.s, 1, 64);
    if (l == 0) { ex.m = NEGINF; ex.s = 0.0f; }
    MS run = ex;
    #pragma unroll
    for (int e = 0; e < 8; e++) {
      int p = l * 8 + e;
      run = ms_add(run, xs[e]);
      sgeq2[(size_t)bi * J_ + (J_ - 1 - p)] = ms_val(run) * LOG2E;
    }
  }
}

// ============ Kernel B: DP over i — pair output (no w materialization) =====
// 1 wave/batch, lane l owns p = l*8+e, 1-deep prefetch (fastest measured).
// Stores (aw = S+Ts, sw = sel) per element; kernelCD reconstructs w.
__global__ __launch_bounds__(64) void kernelB(
    const float* __restrict__ val2, const float* __restrict__ sgeq2,
    const unsigned char* __restrict__ mmask, const float* __restrict__ tratio,
    float* __restrict__ aw, float* __restrict__ sw) {
  const int b = blockIdx.x;
  const int l = threadIdx.x;
  const int p0 = l << 3;

  const float temp = 0.1f + 0.9f * tratio[0];
  const float Tfix = 1442.695f / temp + 40.0f;  // >= max spike + 40

  const bool mbyte = mask_is_byte(mmask);
  float ilimf[8], Atm[8], Asel[8];
#pragma unroll
  for (int e = 0; e < 8; e++) {
    int p = p0 + e;
    bool ok = (p <= J_ - 2) && (mask_get(mmask, b * J_ + p, mbyte) != 0);
    // alpha at position p is live for next-row update iff i <= p-1 AND ok
    ilimf[e] = ok ? (float)(p - 1) : -1.5f;
    Atm[e] = 0.0f;
    Asel[e] = (p == 0) ? 1.0f : 0.0f;   // alpha = Atm + log2(Asel); 0 = -inf
  }

  const float4* sb4 = (const float4*)(sgeq2 + (size_t)b * I_ * J_);
  const float4* vb4 = (const float4*)(val2  + (size_t)b * I_ * J_);
  float* ab = aw + (size_t)b * I_ * J_;
  float* wb = sw + (size_t)b * I_ * J_;

  float4 Sq0 = sb4[l * 2], Sq1 = sb4[l * 2 + 1];
  float4 Vq0 = vb4[l * 2], Vq1 = vb4[l * 2 + 1];

  for (int i = 0; i < I_; i++) {
    // prefetch next row (clamped; redundant reload on last iter harmless)
    const int rn = (i + 1 < I_) ? i + 1 : i;
    const int ro = rn * (J_ / 4);
    float4 Sn0 = sb4[ro + l * 2], Sn1 = sb4[ro + l * 2 + 1];
    float4 Vn0 = vb4[ro + l * 2], Vn1 = vb4[ro + l * 2 + 1];

    float S[8] = {Sq0.x, Sq0.y, Sq0.z, Sq0.w, Sq1.x, Sq1.y, Sq1.z, Sq1.w};
    float V[8] = {Vq0.x, Vq0.y, Vq0.z, Vq0.w, Vq1.x, Vq1.y, Vq1.z, Vq1.w};

    // off-chain: sp1 = S[p+1], spike class (sp1 collapsed), shifted sp1
    float nextS0 = dppf<0x130, 0xf, 0xf, false>(0.0f, S[0]);  // wave_shl:1
    float sp1s[8];
    bool spk[8];
#pragma unroll
    for (int e = 0; e < 8; e++) {
      float sp1 = (e < 7) ? S[e + 1] : nextS0;
      spk[e] = sp1 < CUTF;
      sp1s[e] = spk[e] ? (sp1 + Tfix) : sp1;
    }

    // x = 2^{Atm - sp1s} * Asel  (clamp guards dead-lane garbage: x*0 = 0)
    float h[8], t[8];
#pragma unroll
    for (int e = 0; e < 8; e++) {
      float arg = fminf(Atm[e] - sp1s[e], MIDCLAMP);
      float x = __builtin_amdgcn_exp2f(arg) * Asel[e];
      h[e] = spk[e] ? 0.0f : x;
      t[e] = spk[e] ? x : 0.0f;
    }

    // in-lane inclusive prefixes (two independent chains, ILP)
    float hp[8], tp[8];
    hp[0] = h[0]; tp[0] = t[0];
#pragma unroll
    for (int e = 1; e < 8; e++) { hp[e] = hp[e - 1] + h[e]; tp[e] = tp[e - 1] + t[e]; }

    // wave add-scans of lane totals; exclusive via wave_shr:1 (lane0 -> 0)
    float hincl = wave_incl_add_f(hp[7]);
    float tincl = wave_incl_add_f(tp[7]);
    float hx = dppf<0x138, 0xf, 0xf, false>(0.0f, hincl);
    float tx = dppf<0x138, 0xf, 0xf, false>(0.0f, tincl);

    // C[p-1] as pair (Ts, sel): value = Ts + log2(sel)
    float sel[8], Ts[8], ao[8];
#pragma unroll
    for (int e = 0; e < 8; e++) {
      float pe1 = (e >= 1) ? hx + hp[e - 1] : hx;
      float tv1 = (e >= 1) ? tx + tp[e - 1] : tx;
      bool tl = tv1 > 0.0f;
      sel[e] = tl ? tv1 : pe1;
      Ts[e]  = tl ? Tfix : 0.0f;
      ao[e]  = S[e] + Ts[e];   // w = exp2(ao)*sel + floor, done in kernelCD
    }
    float4* a4 = (float4*)(ab + (size_t)i * J_);
    a4[l * 2]     = make_float4(ao[0], ao[1], ao[2], ao[3]);
    a4[l * 2 + 1] = make_float4(ao[4], ao[5], ao[6], ao[7]);
    float4* s4 = (float4*)(wb + (size_t)i * J_);
    s4[l * 2]     = make_float4(sel[0], sel[1], sel[2], sel[3]);
    s4[l * 2 + 1] = make_float4(sel[4], sel[5], sel[6], sel[7]);

    // alpha_{i+1}[p] = V[p-1] + C[p-2] -> (Atm, Asel) = (V+Ts, sel)[p-1]
    if (i < I_ - 1) {
      float prevV7 = dppf<0x138, 0xf, 0xf, false>(0.0f, V[7]);
      float prevT7 = dppf<0x138, 0xf, 0xf, false>(0.0f, Ts[7]);
      float prevS7 = dppf<0x138, 0xf, 0xf, false>(0.0f, sel[7]);
      float fi = (float)i;
#pragma unroll
      for (int e = 0; e < 8; e++) {
        float vp = (e >= 1) ? V[e - 1]   : prevV7;
        float ts = (e >= 1) ? Ts[e - 1]  : prevT7;
        float sl = (e >= 1) ? sel[e - 1] : prevS7;
        Atm[e] = vp + ts;
        Asel[e] = (fi <= ilimf[e]) ? sl : 0.0f;
      }
    }
    Sq0 = Sn0; Sq1 = Sn1; Vq0 = Vn0; Vq1 = Vn1;
  }
}

// ============ Kernel CD: expanded (blocks < B*J) + delta (rest) ============
// Reconstructs w = exp2(aw)*sw + (J-q)*e^-10 — same f32 ops kernelB used
// to do, bit-identical results.
__global__ __launch_bounds__(256) void kernelCD(
    const float* __restrict__ aw, const float* __restrict__ sw,
    const float* __restrict__ text,
    float* __restrict__ expanded, float* __restrict__ delta) {
  int blk = blockIdx.x;
  if (blk < B_ * J_) {
    int b = blk >> 9, j = blk & (J_ - 1);
    int d = threadIdx.x;
    __shared__ float w_s[I_];
    float fl = (float)(J_ - j) * FLOORK;
    if (d < I_) {
      size_t idx = (size_t)(b * I_ + d) * J_ + j;
      w_s[d] = fmaf(__builtin_amdgcn_exp2f(aw[idx]), sw[idx], fl);
    }
    __syncthreads();
    float acc = 0.0f;
    #pragma unroll 8
    for (int i = 0; i < I_; i++)
      acc += w_s[i] * text[(size_t)(b * I_ + i) * D_ + d];
    expanded[(size_t)(b * J_ + j) * D_ + d] = acc;
  } else {
    int n = (blk - B_ * J_) * 256 + threadIdx.x;  // B*I*J / 256 blocks
    int q = n & (J_ - 1);
    float fl = (float)(J_ - q) * FLOORK;
    float w = fmaf(__builtin_amdgcn_exp2f(aw[n]), sw[n], fl);
    delta[n] = __logf(w);
  }
}

extern "C" void kernel_launch(void* const* d_in, const int* in_sizes, int n_in,
                              void* d_out, int out_size, void* d_ws, size_t ws_size,
                              hipStream_t stream) {
  (void)in_sizes; (void)n_in; (void)out_size; (void)ws_size;
  const float* text = (const float*)d_in[0];
  const float* mel  = (const float*)d_in[1];
  const unsigned char* tmask = (const unsigned char*)d_in[2];
  const unsigned char* mmask = (const unsigned char*)d_in[3];
  const float* tratio = (const float*)d_in[4];

  float* out = (float*)d_out;
  float* delta = out;                                  // B*I*J
  float* expanded = out + (size_t)B_ * I_ * J_;        // B*J*D
  float* val2  = (float*)d_ws;                         // B*I*J (log2 domain)
  float* sgeq2 = val2 + (size_t)B_ * I_ * J_;          // B*I*J (log2 domain)
  float* aw    = sgeq2 + (size_t)B_ * I_ * J_;         // B*I*J (S+Ts)
  float* sw    = aw + (size_t)B_ * I_ * J_;            // B*I*J (sel)

  kernelA<<<B_ * I_, 512, 0, stream>>>(text, mel, tmask, mmask, tratio, val2, sgeq2);
  kernelB<<<B_, 64, 0, stream>>>(val2, sgeq2, mmask, tratio, aw, sw);
  kernelCD<<<B_ * J_ + (B_ * I_ * J_) / 256, 256, 0, stream>>>(
      aw, sw, text, expanded, delta);
}

// Round 17
// 67.757 us; speedup vs baseline: 1.0655x; 1.0655x over previous
//
#include <hip/hip_runtime.h>
#include <hip/hip_bf16.h>
#include <math.h>

// MoBoAligner forward — closed-form O(B*I*J) reformulation.
//
//   val[b,i,j]   = soft_ok ? (dot/256 - log(-log(u)))/temp : -1000
//   S_geq[b,i,k] = LSE_{j>=k} val[b,i,j]                (reverse cum-LSE)
//   g_i[p] = alpha_i[p] - S_geq[i][p+1]  (-inf if p==J-1 or !mel_mask[p])
//   C_i    = prefix cumLSE of g_i
//   alpha_{i+1}[j] = val[i][j-1] + C_i[j-2]    (masked j >= i+1)
//   w[i][q]  = exp(S_geq[i][q] + C_i[q-1]) + (J-q)*e^-10   ( = exp(delta) )
//   delta = log(w)  and  expanded = sum_i w * text   (kernelCD)
//
// r10-r16 ledger: kernelB is issue-bound at the un-ramped clock (~0.7 GHz;
// 4/256 CUs never trigger DVFS); all load/store schedules land within noise.
// r16's pair-output B (stores (S+Ts, sel), CD reconstructs w bit-identically)
// is the fastest B measured — kept verbatim. This round fixes the LAST
// identified serial section: kernelA's tid0 64-iteration mask-count loop
// (serial global loads while 511 threads idle) -> wave ballot + popcount.
//
// Scale analysis (exact): true alpha <= 0, S_geq non-increasing and bimodal
// {normal >= -216, collapsed <= -1434 log2 units for temp in [0.1,1]}.
// Spike classification on S[p+1] < CUTF is off-chain; tail scale
// Tfix = 1442.7/temp + 40 bounds all spikes; collapsed-S positions form a
// suffix, so head/tail prefix sums at two fixed scales are exact to ulp.
// MIDCLAMP guards dead-zone garbage; Asel=0 marks dead alpha.

#define B_ 4
#define I_ 64
#define J_ 512
#define D_ 256

#define NEGINF (-INFINITY)
#define LOG2E 1.4426950408889634f
#define CUTF (-720.0f)     // S bimodal split (log2 units), all temp in [0.1,1]
#define MIDCLAMP 60.0f     // overflow guard for dead-zone / garbage args
#define FLOORK 4.5399929762484854e-05f  // e^-10

// ---------------- Threefry-2x32-20, key = (0, 42) --------------------------
__device__ __forceinline__ void tf2x32(unsigned int x0, unsigned int x1,
                                       unsigned int& y0, unsigned int& y1) {
  const unsigned int k0 = 0u, k1 = 42u;
  const unsigned int k2 = k0 ^ k1 ^ 0x1BD11BDAu;
  x0 += k0; x1 += k1;
#define TFR(r) { x0 += x1; x1 = (x1 << r) | (x1 >> (32 - r)); x1 ^= x0; }
  TFR(13) TFR(15) TFR(26) TFR(6)   x0 += k1; x1 += k2 + 1u;
  TFR(17) TFR(29) TFR(16) TFR(24)  x0 += k2; x1 += k0 + 2u;
  TFR(13) TFR(15) TFR(26) TFR(6)   x0 += k0; x1 += k1 + 3u;
  TFR(17) TFR(29) TFR(16) TFR(24)  x0 += k1; x1 += k2 + 4u;
  TFR(13) TFR(15) TFR(26) TFR(6)   x0 += k2; x1 += k0 + 5u;
#undef TFR
  y0 = x0; y1 = x1;
}

__device__ __forceinline__ unsigned int rand_bits(unsigned int n) {
  unsigned int y0, y1;
  tf2x32(0u, n, y0, y1);
  return y0 ^ y1;
}

// log(-log(u)) with u = jax.random.uniform(key(42), ..., 1e-20, 1.0)[n]
__device__ __forceinline__ float gumbel_term(unsigned int n) {
  unsigned int bits = rand_bits(n);
  float f = __uint_as_float((bits >> 9) | 0x3f800000u) - 1.0f;  // [0,1)
  float u = fmaxf(f + 1e-20f, 1e-20f);
  return logf(-logf(u));
}

// ---------------- streaming logsumexp pairs (kernelA, natural log) ---------
struct MS { float m; float s; };

__device__ __forceinline__ MS ms_comb(MS a, MS b) {
  if (b.m == NEGINF) return a;
  if (a.m == NEGINF) return b;
  MS r;
  if (a.m >= b.m) { r.m = a.m; r.s = a.s + b.s * __expf(b.m - a.m); }
  else            { r.m = b.m; r.s = b.s + a.s * __expf(a.m - b.m); }
  return r;
}
__device__ __forceinline__ MS ms_add(MS a, float x) {
  if (x == NEGINF) return a;
  if (a.m == NEGINF) { MS r; r.m = x; r.s = 1.0f; return r; }
  MS r;
  if (a.m >= x) { r.m = a.m; r.s = a.s + __expf(x - a.m); }
  else          { r.m = x;   r.s = 1.0f + a.s * __expf(a.m - x); }
  return r;
}
__device__ __forceinline__ float ms_val(MS a) {
  if (a.m == NEGINF) return NEGINF;
  return a.m + __logf(a.s);
}

__device__ __forceinline__ MS wave_incl_scan(MS v, int lane) {
  #pragma unroll
  for (int off = 1; off < 64; off <<= 1) {
    float mo = __shfl_up(v.m, off, 64);
    float so = __shfl_up(v.s, off, 64);
    if (lane >= off) { MS o; o.m = mo; o.s = so; v = ms_comb(o, v); }
  }
  return v;
}

// ---------------- DPP helpers (kernelB) ------------------------------------
template<int CTRL, int RM, int BM, bool BC>
__device__ __forceinline__ float dppf(float oldv, float src) {
  return __int_as_float(__builtin_amdgcn_update_dpp(
      __float_as_int(oldv), __float_as_int(src), CTRL, RM, BM, BC));
}

// inclusive float add-scan over 64 lanes (invalid sources contribute 0)
__device__ __forceinline__ float wave_incl_add_f(float x) {
  x += dppf<0x111, 0xf, 0xf, false>(0.0f, x);  // row_shr:1
  x += dppf<0x112, 0xf, 0xf, false>(0.0f, x);  // row_shr:2
  x += dppf<0x114, 0xf, 0xf, false>(0.0f, x);  // row_shr:4
  x += dppf<0x118, 0xf, 0xf, false>(0.0f, x);  // row_shr:8
  x += dppf<0x142, 0xa, 0xf, false>(0.0f, x);  // row_bcast:15 -> rows 1,3
  x += dppf<0x143, 0xc, 0xf, false>(0.0f, x);  // row_bcast:31 -> rows 2,3
  return x;
}

// ---------------- mask helpers (bool-bytes vs int32 auto-detect) -----------
__device__ __forceinline__ bool mask_is_byte(const unsigned char* p) {
  const unsigned int* w = (const unsigned int*)p;
  unsigned int orbits = 0;
  #pragma unroll
  for (int k = 0; k < 16; k++) orbits |= w[k];
  return (orbits & 0xFFFFFF00u) != 0u;  // any high byte set -> byte layout
}
__device__ __forceinline__ int mask_get(const unsigned char* p, int idx, bool isbyte) {
  return isbyte ? (p[idx] != 0) : (((const int*)p)[idx] != 0);
}

// ============ Kernel A: val + S_geq per (b,i) row (stored in log2 domain) ==
__global__ __launch_bounds__(512) void kernelA(
    const float* __restrict__ text, const float* __restrict__ mel,
    const unsigned char* __restrict__ tmask, const unsigned char* __restrict__ mmask,
    const float* __restrict__ tratio,
    float* __restrict__ val2, float* __restrict__ sgeq2) {
  int bi = blockIdx.x;
  int b = bi >> 6, i = bi & 63;
  int tid = threadIdx.x;

  __shared__ float t_s[D_];
  __shared__ float v_s[J_];
  __shared__ int sh_ilen;

  // per-thread (uniform broadcast loads, L1-hit): mask layouts + tok
  const bool tbyte = mask_is_byte(tmask);
  const bool mbyte = mask_is_byte(mmask);
  const int tok = mask_get(tmask, b * I_ + i, tbyte);

  // parallel ilen: wave 0 ballot + popcount (replaces tid0's 64-load loop)
  if (tid < 64) {
    int mk = mask_get(tmask, b * I_ + tid, tbyte);
    unsigned long long bal = __ballot(mk != 0);
    if (tid == 0) sh_ilen = (int)__popcll(bal);
  }
  if (tid < D_) t_s[tid] = text[(size_t)(b * I_ + i) * D_ + tid];
  __syncthreads();

  int j = tid;  // 512 threads = one j each
  const float4* m4 = (const float4*)(mel + (size_t)(b * J_ + j) * D_);
  const float4* t4 = (const float4*)t_s;
  float4 acc; acc.x = acc.y = acc.z = acc.w = 0.0f;
  #pragma unroll 8
  for (int d4 = 0; d4 < D_ / 4; ++d4) {
    float4 a = m4[d4]; float4 t = t4[d4];
    acc.x += a.x * t.x; acc.y += a.y * t.y;
    acc.z += a.z * t.z; acc.w += a.w * t.w;
  }
  float dot = (acc.x + acc.y) + (acc.z + acc.w);

  float temp = 0.1f + 0.9f * tratio[0];
  float gum = gumbel_term((unsigned)((b * I_ + i) * J_ + j));
  float e = (dot * (1.0f / 256.0f) - gum) / temp;
  int mok = mask_get(mmask, b * J_ + j, mbyte);
  int hi = J_ - sh_ilen + i + 1;
  bool ok = (j >= i + 1) && (j <= hi) && mok && tok;
  float v = ok ? e : -1000.0f;
  v_s[j] = v;                                   // natural log domain (internal)
  val2[(size_t)bi * J_ + j] = v * LOG2E;        // log2 domain for kernelB
  __syncthreads();

  // reverse cumulative LSE by wave 0: p = reversed index, lane l owns p=l*8+e
  if (tid < 64) {
    int l = tid;
    float xs[8];
    MS tot; tot.m = NEGINF; tot.s = 0.0f;
    #pragma unroll
    for (int e = 0; e < 8; e++) {
      int p = l * 8 + e;
      xs[e] = v_s[J_ - 1 - p];
      tot = ms_add(tot, xs[e]);
    }
    MS inc = wave_incl_scan(tot, l);
    MS ex; ex.m = __shfl_up(inc.m, 1, 64); ex.s = __shfl_up(inc.s, 1, 64);
    if (l == 0) { ex.m = NEGINF; ex.s = 0.0f; }
    MS run = ex;
    #pragma unroll
    for (int e = 0; e < 8; e++) {
      int p = l * 8 + e;
      run = ms_add(run, xs[e]);
      sgeq2[(size_t)bi * J_ + (J_ - 1 - p)] = ms_val(run) * LOG2E;
    }
  }
}

// ============ Kernel B: DP over i — pair output (no w materialization) =====
// 1 wave/batch, lane l owns p = l*8+e, 1-deep prefetch (fastest measured).
// Stores (aw = S+Ts, sw = sel) per element; kernelCD reconstructs w.
__global__ __launch_bounds__(64) void kernelB(
    const float* __restrict__ val2, const float* __restrict__ sgeq2,
    const unsigned char* __restrict__ mmask, const float* __restrict__ tratio,
    float* __restrict__ aw, float* __restrict__ sw) {
  const int b = blockIdx.x;
  const int l = threadIdx.x;
  const int p0 = l << 3;

  const float temp = 0.1f + 0.9f * tratio[0];
  const float Tfix = 1442.695f / temp + 40.0f;  // >= max spike + 40

  const bool mbyte = mask_is_byte(mmask);
  float ilimf[8], Atm[8], Asel[8];
#pragma unroll
  for (int e = 0; e < 8; e++) {
    int p = p0 + e;
    bool ok = (p <= J_ - 2) && (mask_get(mmask, b * J_ + p, mbyte) != 0);
    // alpha at position p is live for next-row update iff i <= p-1 AND ok
    ilimf[e] = ok ? (float)(p - 1) : -1.5f;
    Atm[e] = 0.0f;
    Asel[e] = (p == 0) ? 1.0f : 0.0f;   // alpha = Atm + log2(Asel); 0 = -inf
  }

  const float4* sb4 = (const float4*)(sgeq2 + (size_t)b * I_ * J_);
  const float4* vb4 = (const float4*)(val2  + (size_t)b * I_ * J_);
  float* ab = aw + (size_t)b * I_ * J_;
  float* wb = sw + (size_t)b * I_ * J_;

  float4 Sq0 = sb4[l * 2], Sq1 = sb4[l * 2 + 1];
  float4 Vq0 = vb4[l * 2], Vq1 = vb4[l * 2 + 1];

  for (int i = 0; i < I_; i++) {
    // prefetch next row (clamped; redundant reload on last iter harmless)
    const int rn = (i + 1 < I_) ? i + 1 : i;
    const int ro = rn * (J_ / 4);
    float4 Sn0 = sb4[ro + l * 2], Sn1 = sb4[ro + l * 2 + 1];
    float4 Vn0 = vb4[ro + l * 2], Vn1 = vb4[ro + l * 2 + 1];

    float S[8] = {Sq0.x, Sq0.y, Sq0.z, Sq0.w, Sq1.x, Sq1.y, Sq1.z, Sq1.w};
    float V[8] = {Vq0.x, Vq0.y, Vq0.z, Vq0.w, Vq1.x, Vq1.y, Vq1.z, Vq1.w};

    // off-chain: sp1 = S[p+1], spike class (sp1 collapsed), shifted sp1
    float nextS0 = dppf<0x130, 0xf, 0xf, false>(0.0f, S[0]);  // wave_shl:1
    float sp1s[8];
    bool spk[8];
#pragma unroll
    for (int e = 0; e < 8; e++) {
      float sp1 = (e < 7) ? S[e + 1] : nextS0;
      spk[e] = sp1 < CUTF;
      sp1s[e] = spk[e] ? (sp1 + Tfix) : sp1;
    }

    // x = 2^{Atm - sp1s} * Asel  (clamp guards dead-lane garbage: x*0 = 0)
    float h[8], t[8];
#pragma unroll
    for (int e = 0; e < 8; e++) {
      float arg = fminf(Atm[e] - sp1s[e], MIDCLAMP);
      float x = __builtin_amdgcn_exp2f(arg) * Asel[e];
      h[e] = spk[e] ? 0.0f : x;
      t[e] = spk[e] ? x : 0.0f;
    }

    // in-lane inclusive prefixes (two independent chains, ILP)
    float hp[8], tp[8];
    hp[0] = h[0]; tp[0] = t[0];
#pragma unroll
    for (int e = 1; e < 8; e++) { hp[e] = hp[e - 1] + h[e]; tp[e] = tp[e - 1] + t[e]; }

    // wave add-scans of lane totals; exclusive via wave_shr:1 (lane0 -> 0)
    float hincl = wave_incl_add_f(hp[7]);
    float tincl = wave_incl_add_f(tp[7]);
    float hx = dppf<0x138, 0xf, 0xf, false>(0.0f, hincl);
    float tx = dppf<0x138, 0xf, 0xf, false>(0.0f, tincl);

    // C[p-1] as pair (Ts, sel): value = Ts + log2(sel)
    float sel[8], Ts[8], ao[8];
#pragma unroll
    for (int e = 0; e < 8; e++) {
      float pe1 = (e >= 1) ? hx + hp[e - 1] : hx;
      float tv1 = (e >= 1) ? tx + tp[e - 1] : tx;
      bool tl = tv1 > 0.0f;
      sel[e] = tl ? tv1 : pe1;
      Ts[e]  = tl ? Tfix : 0.0f;
      ao[e]  = S[e] + Ts[e];   // w = exp2(ao)*sel + floor, done in kernelCD
    }
    float4* a4 = (float4*)(ab + (size_t)i * J_);
    a4[l * 2]     = make_float4(ao[0], ao[1], ao[2], ao[3]);
    a4[l * 2 + 1] = make_float4(ao[4], ao[5], ao[6], ao[7]);
    float4* s4 = (float4*)(wb + (size_t)i * J_);
    s4[l * 2]     = make_float4(sel[0], sel[1], sel[2], sel[3]);
    s4[l * 2 + 1] = make_float4(sel[4], sel[5], sel[6], sel[7]);

    // alpha_{i+1}[p] = V[p-1] + C[p-2] -> (Atm, Asel) = (V+Ts, sel)[p-1]
    if (i < I_ - 1) {
      float prevV7 = dppf<0x138, 0xf, 0xf, false>(0.0f, V[7]);
      float prevT7 = dppf<0x138, 0xf, 0xf, false>(0.0f, Ts[7]);
      float prevS7 = dppf<0x138, 0xf, 0xf, false>(0.0f, sel[7]);
      float fi = (float)i;
#pragma unroll
      for (int e = 0; e < 8; e++) {
        float vp = (e >= 1) ? V[e - 1]   : prevV7;
        float ts = (e >= 1) ? Ts[e - 1]  : prevT7;
        float sl = (e >= 1) ? sel[e - 1] : prevS7;
        Atm[e] = vp + ts;
        Asel[e] = (fi <= ilimf[e]) ? sl : 0.0f;
      }
    }
    Sq0 = Sn0; Sq1 = Sn1; Vq0 = Vn0; Vq1 = Vn1;
  }
}

// ============ Kernel CD: expanded (blocks < B*J) + delta (rest) ============
// Reconstructs w = exp2(aw)*sw + (J-q)*e^-10 — same f32 ops kernelB used
// to do, bit-identical results.
__global__ __launch_bounds__(256) void kernelCD(
    const float* __restrict__ aw, const float* __restrict__ sw,
    const float* __restrict__ text,
    float* __restrict__ expanded, float* __restrict__ delta) {
  int blk = blockIdx.x;
  if (blk < B_ * J_) {
    int b = blk >> 9, j = blk & (J_ - 1);
    int d = threadIdx.x;
    __shared__ float w_s[I_];
    float fl = (float)(J_ - j) * FLOORK;
    if (d < I_) {
      size_t idx = (size_t)(b * I_ + d) * J_ + j;
      w_s[d] = fmaf(__builtin_amdgcn_exp2f(aw[idx]), sw[idx], fl);
    }
    __syncthreads();
    float acc = 0.0f;
    #pragma unroll 8
    for (int i = 0; i < I_; i++)
      acc += w_s[i] * text[(size_t)(b * I_ + i) * D_ + d];
    expanded[(size_t)(b * J_ + j) * D_ + d] = acc;
  } else {
    int n = (blk - B_ * J_) * 256 + threadIdx.x;  // B*I*J / 256 blocks
    int q = n & (J_ - 1);
    float fl = (float)(J_ - q) * FLOORK;
    float w = fmaf(__builtin_amdgcn_exp2f(aw[n]), sw[n], fl);
    delta[n] = __logf(w);
  }
}

extern "C" void kernel_launch(void* const* d_in, const int* in_sizes, int n_in,
                              void* d_out, int out_size, void* d_ws, size_t ws_size,
                              hipStream_t stream) {
  (void)in_sizes; (void)n_in; (void)out_size; (void)ws_size;
  const float* text = (const float*)d_in[0];
  const float* mel  = (const float*)d_in[1];
  const unsigned char* tmask = (const unsigned char*)d_in[2];
  const unsigned char* mmask = (const unsigned char*)d_in[3];
  const float* tratio = (const float*)d_in[4];

  float* out = (float*)d_out;
  float* delta = out;                                  // B*I*J
  float* expanded = out + (size_t)B_ * I_ * J_;        // B*J*D
  float* val2  = (float*)d_ws;                         // B*I*J (log2 domain)
  float* sgeq2 = val2 + (size_t)B_ * I_ * J_;          // B*I*J (log2 domain)
  float* aw    = sgeq2 + (size_t)B_ * I_ * J_;         // B*I*J (S+Ts)
  float* sw    = aw + (size_t)B_ * I_ * J_;            // B*I*J (sel)

  kernelA<<<B_ * I_, 512, 0, stream>>>(text, mel, tmask, mmask, tratio, val2, sgeq2);
  kernelB<<<B_, 64, 0, stream>>>(val2, sgeq2, mmask, tratio, aw, sw);
  kernelCD<<<B_ * J_ + (B_ * I_ * J_) / 256, 256, 0, stream>>>(
      aw, sw, text, expanded, delta);
}